// Round 1
// baseline (573.621 us; speedup 1.0000x reference)
//
#include <hip/hip_runtime.h>

// Laguerre FilterbankCell: y_t = M y_{t-1} + v x_t, K=12 state, output full state each step.
// Chunked parallel linear scan: pass1 chunk-local end states -> pass2 combine via M^L ->
// pass3 re-run chunks from correct initial state, streaming outputs.

#define KF 12
#define GF 2
#define BF 2048
#define SF 2048
#define CHUNKS 32
#define LCH 64          // SF / CHUNKS
#define BG (BF * GF)    // 4096 = 2^12

// ---------------------------------------------------------------------------
// Setup: Mp[g] = M^LCH (K x K), M lower-triangular:
//   M[j][j] = sa;  M[j][m] = -(1 - sa^2) * sa^(j-m-1)  for m < j;  0 above diag.
// Repeated squaring 6x (2^6 = 64 = LCH) in LDS. One block per group, 192 thr.
// ---------------------------------------------------------------------------
__global__ void setup_mpow(const float* __restrict__ relax, float* __restrict__ Mp) {
    const int g = blockIdx.x;
    const int t = threadIdx.x;
    __shared__ float A[KF][KF];
    const float rx = relax[g];
    const float sa = sqrtf(rx);

    if (t < KF * KF) {
        const int j = t / KF, m = t % KF;
        float v = 0.0f;
        if (m == j) {
            v = sa;
        } else if (m < j) {
            float p = 1.0f;
            for (int i = 0; i < j - m - 1; ++i) p *= sa;
            v = -(1.0f - rx) * p;
        }
        A[j][m] = v;
    }
    __syncthreads();

    for (int it = 0; it < 6; ++it) {
        float s = 0.0f;
        if (t < KF * KF) {
            const int j = t / KF, m = t % KF;
            #pragma unroll
            for (int i = 0; i < KF; ++i) s += A[j][i] * A[i][m];
        }
        __syncthreads();
        if (t < KF * KF) A[t / KF][t % KF] = s;
        __syncthreads();
    }

    if (t < KF * KF) Mp[g * KF * KF + t] = A[t / KF][t % KF];
}

// ---------------------------------------------------------------------------
// One recurrence step, fully unrolled. y[] updated in place.
// ---------------------------------------------------------------------------
__device__ __forceinline__ void fb_step(float* y, float xt, float sa, float tsb) {
    float pm1 = y[0];
    y[0] = sa * y[0] + tsb * xt;
    #pragma unroll
    for (int j = 1; j < KF; ++j) {
        const float tmp = y[j];
        y[j] = sa * tmp + sa * y[j - 1] - pm1;
        pm1 = tmp;
    }
}

// ---------------------------------------------------------------------------
// Pass 1: per (b,g,c) run chunk from zero state; store end state F[c][b][g][k].
// tid -> g = tid&1, b = (tid>>1)&2047, c = tid>>12.
// ---------------------------------------------------------------------------
__global__ void pass1_chunk_states(const float* __restrict__ x,
                                   const float* __restrict__ relax,
                                   float* __restrict__ F) {
    const int tid = blockIdx.x * blockDim.x + threadIdx.x;
    const int g = tid & 1;
    const int b = (tid >> 1) & (BF - 1);
    const int c = tid >> 12;

    const float rx = relax[g];
    const float sa = sqrtf(rx);
    const float tsb = sqrtf(1.0f - rx);   // T_SAMP = 1

    float y[KF];
    #pragma unroll
    for (int k = 0; k < KF; ++k) y[k] = 0.0f;

    const float* xp = x + ((size_t)b * SF + (size_t)c * LCH) * GF + g;
    for (int t = 0; t < LCH; ++t) {
        fb_step(y, xp[(size_t)t * GF], sa, tsb);
    }

    float4* Fp = (float4*)(F + (((size_t)c * BF + b) * GF + g) * KF);
    Fp[0] = make_float4(y[0], y[1], y[2],  y[3]);
    Fp[1] = make_float4(y[4], y[5], y[6],  y[7]);
    Fp[2] = make_float4(y[8], y[9], y[10], y[11]);
}

// ---------------------------------------------------------------------------
// Pass 2: per (b,g): s_in(c) = Mp * s_in(c-1) + F(c-1), store into slot c-1.
// 16 lanes per (b,g) group; lane sub<12 owns component k of running state r.
// Matvec via __shfl within the 16-lane group.
// ---------------------------------------------------------------------------
__global__ void pass2_combine(float* __restrict__ F, const float* __restrict__ Mp) {
    const int tid = blockIdx.x * blockDim.x + threadIdx.x;   // BG*16 threads
    const int sub = tid & 15;
    const int bg  = tid >> 4;          // [0, BG)
    const int g   = bg & 1;
    const int lane = threadIdx.x & 63;
    const int grpbase = lane & ~15;

    const int k = (sub < KF) ? sub : 0;
    float Mrow[KF];
    const float* mr = Mp + ((size_t)g * KF + k) * KF;
    #pragma unroll
    for (int m = 0; m < KF; ++m) Mrow[m] = mr[m];

    float r = 0.0f;
    for (int c = 1; c < CHUNKS; ++c) {
        float* slot = F + ((size_t)(c - 1) * BG + bg) * KF + k;
        const float f = *slot;
        float acc = f;
        #pragma unroll
        for (int m = 0; m < KF; ++m) {
            acc += Mrow[m] * __shfl(r, grpbase + m, 64);
        }
        if (sub < KF) *slot = acc;
        r = acc;
    }
}

// ---------------------------------------------------------------------------
// Pass 3: per (b,g,c): load s_in (slot c-1; zeros for c==0), re-run chunk,
// stream outputs (3 x float4 per step, contiguous 48 B).
// ---------------------------------------------------------------------------
__global__ void pass3_outputs(const float* __restrict__ x,
                              const float* __restrict__ relax,
                              const float* __restrict__ F,
                              float* __restrict__ out) {
    const int tid = blockIdx.x * blockDim.x + threadIdx.x;
    const int g = tid & 1;
    const int b = (tid >> 1) & (BF - 1);
    const int c = tid >> 12;

    const float rx = relax[g];
    const float sa = sqrtf(rx);
    const float tsb = sqrtf(1.0f - rx);

    float y[KF];
    if (c == 0) {
        #pragma unroll
        for (int k = 0; k < KF; ++k) y[k] = 0.0f;
    } else {
        const float4* Fp = (const float4*)(F + ((size_t)(c - 1) * BG + (b * GF + g)) * KF);
        const float4 a0 = Fp[0], a1 = Fp[1], a2 = Fp[2];
        y[0] = a0.x; y[1] = a0.y; y[2]  = a0.z; y[3]  = a0.w;
        y[4] = a1.x; y[5] = a1.y; y[6]  = a1.z; y[7]  = a1.w;
        y[8] = a2.x; y[9] = a2.y; y[10] = a2.z; y[11] = a2.w;
    }

    const float* xp = x + ((size_t)b * SF + (size_t)c * LCH) * GF + g;
    float* op = out + (((size_t)b * SF + (size_t)c * LCH) * GF + g) * KF;

    for (int t = 0; t < LCH; ++t) {
        fb_step(y, xp[(size_t)t * GF], sa, tsb);
        float4* o4 = (float4*)(op + (size_t)t * (GF * KF));
        o4[0] = make_float4(y[0], y[1], y[2],  y[3]);
        o4[1] = make_float4(y[4], y[5], y[6],  y[7]);
        o4[2] = make_float4(y[8], y[9], y[10], y[11]);
    }
}

// ---------------------------------------------------------------------------
extern "C" void kernel_launch(void* const* d_in, const int* in_sizes, int n_in,
                              void* d_out, int out_size, void* d_ws, size_t ws_size,
                              hipStream_t stream) {
    const float* x     = (const float*)d_in[0];   // [B,S,G] f32
    const float* relax = (const float*)d_in[1];   // [G] f32
    float* out = (float*)d_out;                   // [B,S,G,K] f32

    float* Mp = (float*)d_ws;                               // G*K*K floats
    float* F  = (float*)((char*)d_ws + 4096);               // CHUNKS*B*G*K floats (~6.3 MB)

    setup_mpow<<<GF, 192, 0, stream>>>(relax, Mp);

    const int threads13 = BG * CHUNKS;                      // 131072
    pass1_chunk_states<<<threads13 / 256, 256, 0, stream>>>(x, relax, F);

    pass2_combine<<<(BG * 16) / 256, 256, 0, stream>>>(F, Mp);

    pass3_outputs<<<threads13 / 256, 256, 0, stream>>>(x, relax, F, out);
}